// Round 2
// baseline (481.895 us; speedup 1.0000x reference)
//
#include <hip/hip_runtime.h>
#include <hip/hip_bf16.h>

using bf16 = __hip_bfloat16;
using floatx4 = __attribute__((ext_vector_type(4))) float;
using bf16x8  = __attribute__((ext_vector_type(8))) __bf16;
using bf16x2  = __attribute__((ext_vector_type(2))) __bf16;

#define MDIM 8192   // B*T
#define NDIM 2048   // C
#define KDIM 2048   // C
#define TSEQ 2048   // T
#define BB   4      // batch
#define CDIM 2048   // C
#define NCHUNK 64
#define TCHUNK 32   // TSEQ/NCHUNK

typedef __attribute__((address_space(1))) void gvoid_t;
typedef __attribute__((address_space(3))) void lvoid_t;

__device__ __forceinline__ void load_lds16(const void* g, void* l) {
  __builtin_amdgcn_global_load_lds((gvoid_t*)(void*)g, (lvoid_t*)l, 16, 0, 0);
}

// ---------------- fp32 -> bf16 convert: all 5 matrices, one launch ------------
__global__ __launch_bounds__(256) void cvt_all(
    const float* __restrict__ x,
    const float* __restrict__ Wk, const float* __restrict__ Wv,
    const float* __restrict__ Wr, const float* __restrict__ Wo,
    __bf16* __restrict__ xb,
    __bf16* __restrict__ wkb, __bf16* __restrict__ wvb,
    __bf16* __restrict__ wrb, __bf16* __restrict__ wob) {
  const size_t WN = (size_t)NDIM * KDIM;
  const int slice = blockIdx.y;
  const float* s;
  __bf16* d;
  if (slice < 4) { s = x + (size_t)slice * WN; d = xb + (size_t)slice * WN; }
  else {
    s = (slice == 4) ? Wk : (slice == 5) ? Wv : (slice == 6) ? Wr : Wo;
    d = (slice == 4) ? wkb : (slice == 5) ? wvb : (slice == 6) ? wrb : wob;
  }
  const int i = (blockIdx.x * 256 + threadIdx.x) * 8;
  float4 a = *(const float4*)(s + i);
  float4 b = *(const float4*)(s + i + 4);
  bf16x8 o;
  o[0] = (__bf16)a.x; o[1] = (__bf16)a.y; o[2] = (__bf16)a.z; o[3] = (__bf16)a.w;
  o[4] = (__bf16)b.x; o[5] = (__bf16)b.y; o[6] = (__bf16)b.z; o[7] = (__bf16)b.w;
  *(bf16x8*)(d + i) = o;
}

// ---------------- GEMM: C[m,n] = sum_k A[m,k] * B[n,k], bf16 in, fp32 acc -----
// 256x256 tile, BK=64, 512 threads = 8 waves (2 M x 4 N).  4 phases per K-tile,
// split by (kk, m-half): ds_reads balanced 8/4/8/4 per phase, 16 MFMA each.
//
// DEEP PIPELINE (region-granularity double buffer):
//   P1 of tile t stages K1 of tile t+1  (that region's last reads COMPLETED
//      before t-1 P4's trailing barrier -> safe).
//   P4 of tile t stages K0 of tile t+2 into the CURRENT buffer's kk=0 region
//      (last reads completed before t P2's trailing barrier, 2 barriers ago).
//   Steady-state waits: vmcnt(8) at P2 (proves K1(t), issued t-1 P1, 4 phases
//   ago) and at P4 (proves K0(t+1), issued t-1 P4, 4 phases ago).  Oldest
//   waited load always has ~4-5 phases (~1000+ cyc) of latency coverage.
//   vmcnt counts instructions: 4 global_load_lds per staging group.
//
// LDS (128 KiB): buf b (b=t&1) at b*32768: A regions (kk,rh) of 8 KiB each;
// B same at +65536.  Row r' (64 B) has four 16-B slots; slot sc holds data
// chunk sc ^ ((r'>>1)&3); global_load_lds dest stays LINEAR (tid*16), the
// swizzle is applied to the per-lane GLOBAL source address.

#define GBARRIER() asm volatile("s_barrier" ::: "memory")
#define VMW8()     asm volatile("s_waitcnt vmcnt(8)" ::: "memory")
#define VMW4()     asm volatile("s_waitcnt vmcnt(4)" ::: "memory")
#define VMW0()     asm volatile("s_waitcnt vmcnt(0)" ::: "memory")

template <typename CT>
__device__ __forceinline__ void gemm256_body(const __bf16* __restrict__ A,
                                             const __bf16* __restrict__ B,
                                             CT* __restrict__ C,
                                             const int bm, const int bn) {
  __shared__ __attribute__((aligned(128))) unsigned char lds[131072];
  const int tid  = threadIdx.x;
  const int lane = tid & 63;
  const int wave = tid >> 6;
  const int wm = wave >> 2;   // 0..1  (M half)
  const int wn = wave & 3;    // 0..3  (N quarter)

  floatx4 acc[8][4] = {};
  bf16x8 af[4], bfr[4];

  // staging: thread tid covers row (tid>>2) of a 128-row region, 16 B at
  // swizzled data chunk ((tid&3) ^ ((tid>>3)&3))
  const int srow = tid >> 2;
  const int scol = ((tid & 3) ^ ((tid >> 3) & 3)) * 8;
  const __bf16* Ag = A + (size_t)(bm * 256 + srow) * KDIM + scol;
  const __bf16* Bg = B + (size_t)(bn * 256 + srow) * KDIM + scol;
  const uint32_t sdst = (uint32_t)tid * 16u;

  // frag-read lane offset: row (lane&15), slot (lane>>4) ^ ((lane>>1)&3)
  const uint32_t laneoff =
      (uint32_t)((lane & 15) * 64 + (((lane >> 4) ^ ((lane >> 1) & 3)) * 16));
  const uint32_t aoff = (uint32_t)(wm * 8192) + laneoff;
  const uint32_t boff = 65536u +
      (uint32_t)((wn >> 1) * 8192 + (wn & 1) * 4096) + laneoff;

#define STG_A(bf_, kt_, kk_, rh_)                                             \
  load_lds16(Ag + (size_t)(rh_) * 128 * KDIM + (size_t)((kt_) * 64 + (kk_) * 32), \
             (void*)(lds + (bf_) + (kk_) * 16384u + (rh_) * 8192u + sdst))
#define STG_B(bf_, kt_, kk_, rh_)                                             \
  load_lds16(Bg + (size_t)(rh_) * 128 * KDIM + (size_t)((kt_) * 64 + (kk_) * 32), \
             (void*)(lds + 65536u + (bf_) + (kk_) * 16384u + (rh_) * 8192u + sdst))
// stage one full K-half (A rh0, rh1, B rh0, rh1) = 4 instructions
#define STG_KH(bf_, kt_, kk_) {                                               \
  STG_A(bf_, kt_, kk_, 0); STG_A(bf_, kt_, kk_, 1);                           \
  STG_B(bf_, kt_, kk_, 0); STG_B(bf_, kt_, kk_, 1); }
#define RD_A(kk_, mh_, bo_) {                                                 \
  const uint32_t ab = (bo_) + (kk_) * 16384u + (mh_) * 4096u + aoff;          \
  af[0] = *(const bf16x8*)(lds + ab);        af[1] = *(const bf16x8*)(lds + ab + 1024); \
  af[2] = *(const bf16x8*)(lds + ab + 2048); af[3] = *(const bf16x8*)(lds + ab + 3072); }
#define RD_B(kk_, bo_) {                                                      \
  const uint32_t bb = (bo_) + (kk_) * 16384u + boff;                          \
  bfr[0] = *(const bf16x8*)(lds + bb);        bfr[1] = *(const bf16x8*)(lds + bb + 1024); \
  bfr[2] = *(const bf16x8*)(lds + bb + 2048); bfr[3] = *(const bf16x8*)(lds + bb + 3072); }
#define MFMA16(mh_) {                                                         \
  __builtin_amdgcn_s_setprio(1);                                              \
  _Pragma("unroll")                                                           \
  for (int i_ = 0; i_ < 4; ++i_) {                                            \
    _Pragma("unroll")                                                         \
    for (int j_ = 0; j_ < 4; ++j_)                                            \
      acc[(mh_) * 4 + i_][j_] = __builtin_amdgcn_mfma_f32_16x16x32_bf16(      \
          af[i_], bfr[j_], acc[(mh_) * 4 + i_][j_], 0, 0, 0);                 \
  }                                                                           \
  __builtin_amdgcn_s_setprio(0); }

  // ---- prologue: stage K0(t0), K1(t0), K0(t1)  (12 instructions)
  STG_KH(0u, 0, 0);
  STG_KH(0u, 0, 1);
  STG_KH(32768u, 1, 0);
  VMW8();        // K0(t0) landed; K1(t0)+K0(t1) may stay in flight
  GBARRIER();

  constexpr int NT = KDIM / 64;   // 32
  for (int t = 0; t < NT - 2; ++t) {
    const uint32_t bo  = (uint32_t)(t & 1) * 32768u;
    const uint32_t bo1 = bo ^ 32768u;
    // P1: kk0, m-half0 ; stage K1(t+1) (region idle since t-1 P4 barrier)
    RD_A(0, 0, bo); RD_B(0, bo);
    STG_KH(bo1, t + 1, 1);
    GBARRIER();
    MFMA16(0);
    GBARRIER();
    // P2: kk0, m-half1 (bfr reused) ; prove K1(t) (issued t-1 P1, 8 newer)
    RD_A(0, 1, bo);
    VMW8();
    GBARRIER();
    MFMA16(1);
    GBARRIER();
    // P3: kk1, m-half0
    RD_A(1, 0, bo); RD_B(1, bo);
    GBARRIER();
    MFMA16(0);
    GBARRIER();
    // P4: kk1, m-half1 ; stage K0(t+2) into CURRENT buf kk0 (idle since P2
    //     trailing barrier) ; prove K0(t+1) (issued t-1 P4, 8 newer)
    RD_A(1, 1, bo);
    STG_KH(bo, t + 2, 0);
    VMW8();
    GBARRIER();
    MFMA16(1);
    GBARRIER();
  }
  { // ---- tile NT-2: stage only K1(NT-1); waits shrink
    const uint32_t bo  = (uint32_t)((NT - 2) & 1) * 32768u;
    const uint32_t bo1 = bo ^ 32768u;
    RD_A(0, 0, bo); RD_B(0, bo);
    STG_KH(bo1, NT - 1, 1);
    GBARRIER();
    MFMA16(0);
    GBARRIER();
    RD_A(0, 1, bo);
    VMW8();        // newer: K0(NT-1) [4] + K1(NT-1) [4] -> K1(NT-2) landed
    GBARRIER();
    MFMA16(1);
    GBARRIER();
    RD_A(1, 0, bo); RD_B(1, bo);
    GBARRIER();
    MFMA16(0);
    GBARRIER();
    RD_A(1, 1, bo);
    VMW4();        // newer: K1(NT-1) [4] -> K0(NT-1) landed
    GBARRIER();
    MFMA16(1);
    GBARRIER();
  }
  { // ---- tile NT-1: no staging; single cross-wave guarantee for K1(NT-1)
    const uint32_t bo = (uint32_t)((NT - 1) & 1) * 32768u;
    RD_A(0, 0, bo); RD_B(0, bo);
    MFMA16(0);
    RD_A(0, 1, bo);
    MFMA16(1);
    VMW0();
    GBARRIER();
    RD_A(1, 0, bo); RD_B(1, bo);
    MFMA16(0);
    RD_A(1, 1, bo);
    MFMA16(1);
  }

  // C/D layout: col = lane&15, row = (lane>>4)*4 + reg
  const int crow = (lane >> 4) * 4;
  const int ccol = lane & 15;
#pragma unroll
  for (int i = 0; i < 8; ++i)
#pragma unroll
    for (int j = 0; j < 4; ++j) {
      const size_t r0 = (size_t)(bm * 256 + wm * 128 + i * 16 + crow);
      const int    c0 = bn * 256 + wn * 64 + j * 16 + ccol;
#pragma unroll
      for (int rg = 0; rg < 4; ++rg)
        C[(r0 + rg) * NDIM + c0] = (CT)(acc[i][j][rg]);
    }
#undef STG_A
#undef STG_B
#undef STG_KH
#undef RD_A
#undef RD_B
#undef MFMA16
}

// XCD-aware bijective swizzle: each XCD owns one bn column per z-slice ->
// its B-panels (<=3 MB) stay L2-resident.
__device__ __forceinline__ void xcd_swz(int& bm, int& bn) {
  const int f = (int)(blockIdx.y * 32 + blockIdx.x);   // 0..255
  const int s = (f & 7) * 32 + (f >> 3);
  bm = s & 31;
  bn = s >> 5;
}

__global__ __launch_bounds__(512, 2) void gemm_qkv(const __bf16* __restrict__ x,
                                                   const __bf16* __restrict__ Wk,
                                                   const __bf16* __restrict__ Wv,
                                                   const __bf16* __restrict__ Wr,
                                                   __bf16* __restrict__ kb,
                                                   __bf16* __restrict__ vb,
                                                   __bf16* __restrict__ rb) {
  const __bf16* Bsel = (blockIdx.z == 0) ? Wk : (blockIdx.z == 1) ? Wv : Wr;
  __bf16*       Csel = (blockIdx.z == 0) ? kb : (blockIdx.z == 1) ? vb : rb;
  int bm, bn; xcd_swz(bm, bn);
  gemm256_body<__bf16>(x, Bsel, Csel, bm, bn);
}

__global__ __launch_bounds__(512, 2) void gemm_o(const __bf16* __restrict__ A,
                                                 const __bf16* __restrict__ B,
                                                 float* __restrict__ C) {
  int bm, bn; xcd_swz(bm, bn);
  gemm256_body<float>(A, B, C, bm, bn);
}

// ---------------- WKV blocked scan (3-phase), 2 channels/thread ----------------
__global__ __launch_bounds__(256) void wkv_summary(
    const __bf16* __restrict__ kb, const __bf16* __restrict__ vb,
    const float* __restrict__ td, const float* __restrict__ tf,
    float* __restrict__ nsum, float* __restrict__ dsum) {
  const int c0 = (blockIdx.x * 256 + threadIdx.x) * 2;
  const int chunk = blockIdx.y;
  const int b = blockIdx.z;
  const float dc0 = __expf(-__expf(td[c0]));
  const float dc1 = __expf(-__expf(td[c0 + 1]));
  const float fi0 = __expf(tf[c0]);
  const float fi1 = __expf(tf[c0 + 1]);
  size_t base = ((size_t)b * TSEQ + (size_t)chunk * TCHUNK) * CDIM + c0;
  float n0 = 0.f, d0 = 0.f, n1 = 0.f, d1 = 0.f;
#pragma unroll 4
  for (int t = 0; t < TCHUNK; ++t) {
    bf16x2 k2 = *(const bf16x2*)(kb + base + (size_t)t * CDIM);
    bf16x2 v2 = *(const bf16x2*)(vb + base + (size_t)t * CDIM);
    float k0f = fminf(fmaxf((float)k2[0], -10.f), 10.f);
    float k1f = fminf(fmaxf((float)k2[1], -10.f), 10.f);
    float w0 = __expf(k0f), w1 = __expf(k1f);
    if (chunk == 0 && t == 0) { w0 *= fi0; w1 *= fi1; }
    n0 = dc0 * n0 + w0 * (float)v2[0];
    d0 = dc0 * d0 + w0;
    n1 = dc1 * n1 + w1 * (float)v2[1];
    d1 = dc1 * d1 + w1;
  }
  const size_t si = (size_t)(chunk * BB + b) * CDIM + c0;
  *(float2*)(nsum + si) = make_float2(n0, n1);
  *(float2*)(dsum + si) = make_float2(d0, d1);
}

__global__ __launch_bounds__(256) void wkv_scan(
    const float* __restrict__ td,
    float* __restrict__ nsum, float* __restrict__ dsum) {
  const int c0 = (blockIdx.x * 256 + threadIdx.x) * 2;
  const int b = blockIdx.y;
  const float dT0 = __expf(-__expf(td[c0]) * (float)TCHUNK);
  const float dT1 = __expf(-__expf(td[c0 + 1]) * (float)TCHUNK);
  float pn0 = 0.f, pd0 = 0.f, pn1 = 0.f, pd1 = 0.f;
  for (int j = 0; j < NCHUNK; ++j) {
    const size_t si = (size_t)(j * BB + b) * CDIM + c0;
    float2 Sn = *(const float2*)(nsum + si);
    float2 Sd = *(const float2*)(dsum + si);
    *(float2*)(nsum + si) = make_float2(pn0, pn1);
    *(float2*)(dsum + si) = make_float2(pd0, pd1);
    pn0 = dT0 * pn0 + Sn.x;  pn1 = dT1 * pn1 + Sn.y;
    pd0 = dT0 * pd0 + Sd.x;  pd1 = dT1 * pd1 + Sd.y;
  }
}

__global__ __launch_bounds__(256) void wkv_apply(
    const __bf16* __restrict__ kb, const __bf16* __restrict__ vb,
    __bf16* __restrict__ rb,
    const float* __restrict__ td, const float* __restrict__ tf,
    const float* __restrict__ nsum, const float* __restrict__ dsum) {
  const int c0 = (blockIdx.x * 256 + threadIdx.x) * 2;
  const int chunk = blockIdx.y;
  const int b = blockIdx.z;
  const float dc0 = __expf(-__expf(td[c0]));
  const float dc1 = __expf(-__expf(td[c0 + 1]));
  const float fi0 = __expf(tf[c0]);
  const float fi1 = __expf(tf[c0 + 1]);

  const size_t si = (size_t)(chunk * BB + b) * CDIM + c0;
  float2 pn = *(const float2*)(nsum + si);
  float2 pd = *(const float2*)(dsum + si);
  float n0 = pn.x, n1 = pn.y, d0 = pd.x, d1 = pd.y;

  size_t base = ((size_t)b * TSEQ + (size_t)chunk * TCHUNK) * CDIM + c0;
#pragma unroll 2
  for (int t = 0; t < TCHUNK; ++t) {
    const size_t idx = base + (size_t)t * CDIM;
    bf16x2 k2 = *(const bf16x2*)(kb + idx);
    bf16x2 v2 = *(const bf16x2*)(vb + idx);
    bf16x2 r2 = *(const bf16x2*)(rb + idx);
    float k0f = fminf(fmaxf((float)k2[0], -10.f), 10.f);
    float k1f = fminf(fmaxf((float)k2[1], -10.f), 10.f);
    float w0 = __expf(k0f), w1 = __expf(k1f);
    if (chunk == 0 && t == 0) { w0 *= fi0; w1 *= fi1; }
    n0 = dc0 * n0 + w0 * (float)v2[0];
    d0 = dc0 * d0 + w0;
    n1 = dc1 * n1 + w1 * (float)v2[1];
    d1 = dc1 * d1 + w1;
    const float wkv0 = n0 * __builtin_amdgcn_rcpf(d0 + 1e-6f);
    const float wkv1 = n1 * __builtin_amdgcn_rcpf(d1 + 1e-6f);
    const float sr0 = __builtin_amdgcn_rcpf(1.f + __expf(-(float)r2[0]));
    const float sr1 = __builtin_amdgcn_rcpf(1.f + __expf(-(float)r2[1]));
    bf16x2 o;
    o[0] = (__bf16)(sr0 * wkv0);
    o[1] = (__bf16)(sr1 * wkv1);
    *(bf16x2*)(rb + idx) = o;
  }
}

// ---------------- launch -------------------------------------------------------
extern "C" void kernel_launch(void* const* d_in, const int* in_sizes, int n_in,
                              void* d_out, int out_size, void* d_ws, size_t ws_size,
                              hipStream_t stream) {
  const float* x  = (const float*)d_in[0];
  const float* Wk = (const float*)d_in[1];
  const float* Wv = (const float*)d_in[2];
  const float* Wr = (const float*)d_in[3];
  const float* Wo = (const float*)d_in[4];
  const float* td = (const float*)d_in[5];
  const float* tf = (const float*)d_in[6];
  float* out = (float*)d_out;

  char* ws = (char*)d_ws;
  const size_t matX = (size_t)MDIM * KDIM * sizeof(__bf16);  // 33.5 MB
  const size_t matW = (size_t)NDIM * KDIM * sizeof(__bf16);  // 8.4 MB
  __bf16* xb  = (__bf16*)(ws);
  __bf16* wkb = (__bf16*)(ws + matX);
  __bf16* wvb = (__bf16*)(ws + matX + matW);
  __bf16* wrb = (__bf16*)(ws + matX + 2 * matW);
  __bf16* wob = (__bf16*)(ws + matX + 3 * matW);
  __bf16* kb  = (__bf16*)(ws + matX + 4 * matW);
  __bf16* vb  = (__bf16*)(ws + 2 * matX + 4 * matW);
  __bf16* rb  = (__bf16*)(ws + 3 * matX + 4 * matW);
  float* nsum = (float*)(ws + 4 * matX + 4 * matW);
  float* dsum = nsum + (size_t)NCHUNK * BB * CDIM;

  dim3 blk(256);
  dim3 blk5(512);
  cvt_all<<<dim3(NDIM * KDIM / (8 * 256), 8), blk, 0, stream>>>(
      x, Wk, Wv, Wr, Wo, xb, wkb, wvb, wrb, wob);

  dim3 gq(MDIM / 256, NDIM / 256, 3);
  gemm_qkv<<<gq, blk5, 0, stream>>>(xb, wkb, wvb, wrb, kb, vb, rb);
  dim3 gw(CDIM / 512, NCHUNK, BB);
  wkv_summary<<<gw, blk, 0, stream>>>(kb, vb, td, tf, nsum, dsum);
  wkv_scan<<<dim3(CDIM / 512, BB), blk, 0, stream>>>(td, nsum, dsum);
  wkv_apply<<<gw, blk, 0, stream>>>(kb, vb, rb, td, tf, nsum, dsum);
  dim3 go(MDIM / 256, NDIM / 256, 1);
  gemm_o<<<go, blk5, 0, stream>>>(rb, wob, out);
}

// Round 3
// 468.433 us; speedup vs baseline: 1.0287x; 1.0287x over previous
//
#include <hip/hip_runtime.h>
#include <hip/hip_bf16.h>

using bf16 = __hip_bfloat16;
using floatx4 = __attribute__((ext_vector_type(4))) float;
using bf16x8  = __attribute__((ext_vector_type(8))) __bf16;
using bf16x2  = __attribute__((ext_vector_type(2))) __bf16;

#define MDIM 8192   // B*T
#define NDIM 2048   // C
#define KDIM 2048   // C
#define TSEQ 2048   // T
#define BB   4      // batch
#define CDIM 2048   // C
#define NCHUNK 64
#define TCHUNK 32   // TSEQ/NCHUNK

typedef __attribute__((address_space(1))) void gvoid_t;
typedef __attribute__((address_space(3))) void lvoid_t;

__device__ __forceinline__ void load_lds16(const void* g, void* l) {
  __builtin_amdgcn_global_load_lds((gvoid_t*)(void*)g, (lvoid_t*)l, 16, 0, 0);
}

// ---------------- fp32 -> bf16 convert: all 5 matrices, one launch ------------
__global__ __launch_bounds__(256) void cvt_all(
    const float* __restrict__ x,
    const float* __restrict__ Wk, const float* __restrict__ Wv,
    const float* __restrict__ Wr, const float* __restrict__ Wo,
    __bf16* __restrict__ xb,
    __bf16* __restrict__ wkb, __bf16* __restrict__ wvb,
    __bf16* __restrict__ wrb, __bf16* __restrict__ wob) {
  const size_t WN = (size_t)NDIM * KDIM;
  const int slice = blockIdx.y;
  const float* s;
  __bf16* d;
  if (slice < 4) { s = x + (size_t)slice * WN; d = xb + (size_t)slice * WN; }
  else {
    s = (slice == 4) ? Wk : (slice == 5) ? Wv : (slice == 6) ? Wr : Wo;
    d = (slice == 4) ? wkb : (slice == 5) ? wvb : (slice == 6) ? wrb : wob;
  }
  const int i = (blockIdx.x * 256 + threadIdx.x) * 8;
  float4 a = *(const float4*)(s + i);
  float4 b = *(const float4*)(s + i + 4);
  bf16x8 o;
  o[0] = (__bf16)a.x; o[1] = (__bf16)a.y; o[2] = (__bf16)a.z; o[3] = (__bf16)a.w;
  o[4] = (__bf16)b.x; o[5] = (__bf16)b.y; o[6] = (__bf16)b.z; o[7] = (__bf16)b.w;
  *(bf16x8*)(d + i) = o;
}

// ---------------- GEMM: C[m,n] = sum_k A[m,k] * B[n,k], bf16 in, fp32 acc -----
// 256x256 tile, BK=32, 512 threads = 8 waves (2 M x 4 N).  Per K-tile: 2 phases
// split by n-half (R1's measured-best rhythm: 10/2 ds_reads, 2 staging loads
// and 16 MFMA per phase, 2 barriers per phase).
//
// QUAD-BUFFERED LDS (4 x 32 KiB = 128 KiB): buffer (t&3) holds tile t.
//   Tile t stages tile t+3:  P1 -> A(t+3) [2 loads],  P2 -> B(t+3) [2 loads].
//   ONE wait per tile: vmcnt(8) at P2.  In-flight stack there = 12 loads
//   (tiles t+1, t+2, t+3); retiring to 8 proves A(t+1)+B(t+1) -- issued
//   4-5 phases (~600-750 cyc) before first consumption at t+1 P1.
//   Buffer-overwrite safety: stage into buf (t+3)&3 = (t-1)&3, whose last
//   ds_reads drained before tile t-1 P2's trailing barrier (>=1 barrier
//   before the store issue).
//
// Buffer layout (32 KiB): A [256 rows][64 B] at +0, B same at +16384.
// Row r (64 B) has four 16-B slots; slot sc holds data chunk sc ^ ((r>>1)&3);
// global_load_lds dest stays LINEAR (tid*16), the swizzle is applied to the
// per-lane GLOBAL source address (both-sides-or-neither).  Frag reads
// (ds_read_b128) are a perfect 1 KiB cover per wave -> conflict-free
// (SQ_LDS_BANK_CONFLICT == 0 measured in R1/R2).

#define GBARRIER() asm volatile("s_barrier" ::: "memory")
#define VMW8()     asm volatile("s_waitcnt vmcnt(8)" ::: "memory")
#define VMW4()     asm volatile("s_waitcnt vmcnt(4)" ::: "memory")
#define VMW0()     asm volatile("s_waitcnt vmcnt(0)" ::: "memory")

template <typename CT>
__device__ __forceinline__ void gemm256_body(const __bf16* __restrict__ A,
                                             const __bf16* __restrict__ B,
                                             CT* __restrict__ C,
                                             const int bm, const int bn) {
  __shared__ __attribute__((aligned(128))) unsigned char lds[131072];
  const int tid  = threadIdx.x;
  const int lane = tid & 63;
  const int wave = tid >> 6;
  const int wm = wave >> 2;   // 0..1  (M half)
  const int wn = wave & 3;    // 0..3  (N quarter)

  floatx4 acc[8][4] = {};
  bf16x8 af[8], bfr[2];

  // staging: thread tid covers row (tid>>2) of a 128-row half, 16 B at
  // swizzled data chunk ((tid&3) ^ ((tid>>3)&3))
  const int srow = tid >> 2;
  const int scol = ((tid & 3) ^ ((tid >> 3) & 3)) * 8;
  const __bf16* Ag = A + (size_t)(bm * 256 + srow) * KDIM + scol;
  const __bf16* Bg = B + (size_t)(bn * 256 + srow) * KDIM + scol;
  const uint32_t sdst = (uint32_t)tid * 16u;

  // frag-read lane offset: row (lane&15), slot (lane>>4) ^ ((lane>>1)&3)
  const uint32_t laneoff =
      (uint32_t)((lane & 15) * 64 + (((lane >> 4) ^ ((lane >> 1) & 3)) * 16));
  const uint32_t aoff = (uint32_t)(wm * 8192) + laneoff;
  const uint32_t boff = 16384u + (uint32_t)(wn * 4096) + laneoff;

#define BUF(t_) ((uint32_t)((t_) & 3) * 32768u)
#define STG_A(t_) {                                                           \
  load_lds16(Ag + (size_t)(t_) * 32,                                          \
             (void*)(lds + BUF(t_) + sdst));                                  \
  load_lds16(Ag + (size_t)128 * KDIM + (size_t)(t_) * 32,                     \
             (void*)(lds + BUF(t_) + 8192u + sdst)); }
#define STG_B(t_) {                                                           \
  load_lds16(Bg + (size_t)(t_) * 32,                                          \
             (void*)(lds + BUF(t_) + 16384u + sdst));                         \
  load_lds16(Bg + (size_t)128 * KDIM + (size_t)(t_) * 32,                     \
             (void*)(lds + BUF(t_) + 24576u + sdst)); }
#define RD_AF(bo_) {                                                          \
  const uint32_t ab = (bo_) + aoff;                                           \
  af[0] = *(const bf16x8*)(lds + ab);        af[1] = *(const bf16x8*)(lds + ab + 1024); \
  af[2] = *(const bf16x8*)(lds + ab + 2048); af[3] = *(const bf16x8*)(lds + ab + 3072); \
  af[4] = *(const bf16x8*)(lds + ab + 4096); af[5] = *(const bf16x8*)(lds + ab + 5120); \
  af[6] = *(const bf16x8*)(lds + ab + 6144); af[7] = *(const bf16x8*)(lds + ab + 7168); }
#define RD_BF(bo_, nh_) {                                                     \
  const uint32_t bb = (bo_) + boff + (nh_) * 2048u;                           \
  bfr[0] = *(const bf16x8*)(lds + bb);                                        \
  bfr[1] = *(const bf16x8*)(lds + bb + 1024); }
#define MFMA16(j0_) {                                                         \
  __builtin_amdgcn_s_setprio(1);                                              \
  _Pragma("unroll")                                                           \
  for (int m_ = 0; m_ < 8; ++m_) {                                            \
    acc[m_][(j0_)]     = __builtin_amdgcn_mfma_f32_16x16x32_bf16(af[m_], bfr[0], acc[m_][(j0_)], 0, 0, 0);     \
    acc[m_][(j0_) + 1] = __builtin_amdgcn_mfma_f32_16x16x32_bf16(af[m_], bfr[1], acc[m_][(j0_) + 1], 0, 0, 0); \
  }                                                                           \
  __builtin_amdgcn_s_setprio(0); }

  // ---- prologue: stage tiles 0,1,2 (12 loads); prove tile 0
  STG_A(0); STG_B(0);
  STG_A(1); STG_B(1);
  STG_A(2); STG_B(2);
  VMW8();        // retires A(0)+B(0); tiles 1,2 stay in flight
  GBARRIER();

  constexpr int NT = KDIM / 32;   // 64
  for (int t = 0; t < NT - 3; ++t) {
    const uint32_t bo = BUF(t);
    // P1: n-half0 ; stage A(t+3)
    RD_AF(bo); RD_BF(bo, 0);
    STG_A(t + 3);
    GBARRIER();
    MFMA16(0);
    GBARRIER();
    // P2: n-half1 ; stage B(t+3) ; prove tile t+1 (12 in flight -> 8)
    RD_BF(bo, 1);
    STG_B(t + 3);
    VMW8();
    GBARRIER();
    MFMA16(2);
    GBARRIER();
  }
  { // ---- tile NT-3: no staging; prove NT-2 (8 in flight -> 4)
    const uint32_t bo = BUF(NT - 3);
    RD_AF(bo); RD_BF(bo, 0);
    GBARRIER();
    MFMA16(0);
    GBARRIER();
    RD_BF(bo, 1);
    VMW4();
    GBARRIER();
    MFMA16(2);
    GBARRIER();
  }
  { // ---- tile NT-2: prove NT-1 (loads are 6+ phases old -> cheap drain)
    const uint32_t bo = BUF(NT - 2);
    RD_AF(bo); RD_BF(bo, 0);
    GBARRIER();
    MFMA16(0);
    GBARRIER();
    RD_BF(bo, 1);
    VMW0();
    GBARRIER();
    MFMA16(2);
    GBARRIER();
  }
  { // ---- tile NT-1: nothing outstanding; no barriers needed
    const uint32_t bo = BUF(NT - 1);
    RD_AF(bo); RD_BF(bo, 0);
    MFMA16(0);
    RD_BF(bo, 1);
    MFMA16(2);
  }

  // C/D layout: col = lane&15, row = (lane>>4)*4 + reg
  const int crow = (lane >> 4) * 4;
  const int ccol = lane & 15;
#pragma unroll
  for (int i = 0; i < 8; ++i)
#pragma unroll
    for (int j = 0; j < 4; ++j) {
      const size_t r0 = (size_t)(bm * 256 + wm * 128 + i * 16 + crow);
      const int    c0 = bn * 256 + wn * 64 + j * 16 + ccol;
#pragma unroll
      for (int rg = 0; rg < 4; ++rg)
        C[(r0 + rg) * NDIM + c0] = (CT)(acc[i][j][rg]);
    }
#undef BUF
#undef STG_A
#undef STG_B
#undef RD_AF
#undef RD_BF
#undef MFMA16
}

// XCD-aware bijective swizzle: each XCD owns one bn column per z-slice ->
// its B-panels stay L2-resident.
__device__ __forceinline__ void xcd_swz(int& bm, int& bn) {
  const int f = (int)(blockIdx.y * 32 + blockIdx.x);   // 0..255
  const int s = (f & 7) * 32 + (f >> 3);
  bm = s & 31;
  bn = s >> 5;
}

__global__ __launch_bounds__(512, 2) void gemm_qkv(const __bf16* __restrict__ x,
                                                   const __bf16* __restrict__ Wk,
                                                   const __bf16* __restrict__ Wv,
                                                   const __bf16* __restrict__ Wr,
                                                   __bf16* __restrict__ kb,
                                                   __bf16* __restrict__ vb,
                                                   __bf16* __restrict__ rb) {
  const __bf16* Bsel = (blockIdx.z == 0) ? Wk : (blockIdx.z == 1) ? Wv : Wr;
  __bf16*       Csel = (blockIdx.z == 0) ? kb : (blockIdx.z == 1) ? vb : rb;
  int bm, bn; xcd_swz(bm, bn);
  gemm256_body<__bf16>(x, Bsel, Csel, bm, bn);
}

__global__ __launch_bounds__(512, 2) void gemm_o(const __bf16* __restrict__ A,
                                                 const __bf16* __restrict__ B,
                                                 float* __restrict__ C) {
  int bm, bn; xcd_swz(bm, bn);
  gemm256_body<float>(A, B, C, bm, bn);
}

// ---------------- WKV blocked scan (3-phase), 2 channels/thread ----------------
__global__ __launch_bounds__(256) void wkv_summary(
    const __bf16* __restrict__ kb, const __bf16* __restrict__ vb,
    const float* __restrict__ td, const float* __restrict__ tf,
    float* __restrict__ nsum, float* __restrict__ dsum) {
  const int c0 = (blockIdx.x * 256 + threadIdx.x) * 2;
  const int chunk = blockIdx.y;
  const int b = blockIdx.z;
  const float dc0 = __expf(-__expf(td[c0]));
  const float dc1 = __expf(-__expf(td[c0 + 1]));
  const float fi0 = __expf(tf[c0]);
  const float fi1 = __expf(tf[c0 + 1]);
  size_t base = ((size_t)b * TSEQ + (size_t)chunk * TCHUNK) * CDIM + c0;
  float n0 = 0.f, d0 = 0.f, n1 = 0.f, d1 = 0.f;
#pragma unroll 4
  for (int t = 0; t < TCHUNK; ++t) {
    bf16x2 k2 = *(const bf16x2*)(kb + base + (size_t)t * CDIM);
    bf16x2 v2 = *(const bf16x2*)(vb + base + (size_t)t * CDIM);
    float k0f = fminf(fmaxf((float)k2[0], -10.f), 10.f);
    float k1f = fminf(fmaxf((float)k2[1], -10.f), 10.f);
    float w0 = __expf(k0f), w1 = __expf(k1f);
    if (chunk == 0 && t == 0) { w0 *= fi0; w1 *= fi1; }
    n0 = dc0 * n0 + w0 * (float)v2[0];
    d0 = dc0 * d0 + w0;
    n1 = dc1 * n1 + w1 * (float)v2[1];
    d1 = dc1 * d1 + w1;
  }
  const size_t si = (size_t)(chunk * BB + b) * CDIM + c0;
  *(float2*)(nsum + si) = make_float2(n0, n1);
  *(float2*)(dsum + si) = make_float2(d0, d1);
}

__global__ __launch_bounds__(256) void wkv_scan(
    const float* __restrict__ td,
    float* __restrict__ nsum, float* __restrict__ dsum) {
  const int c0 = (blockIdx.x * 256 + threadIdx.x) * 2;
  const int b = blockIdx.y;
  const float dT0 = __expf(-__expf(td[c0]) * (float)TCHUNK);
  const float dT1 = __expf(-__expf(td[c0 + 1]) * (float)TCHUNK);
  float pn0 = 0.f, pd0 = 0.f, pn1 = 0.f, pd1 = 0.f;
  for (int j = 0; j < NCHUNK; ++j) {
    const size_t si = (size_t)(j * BB + b) * CDIM + c0;
    float2 Sn = *(const float2*)(nsum + si);
    float2 Sd = *(const float2*)(dsum + si);
    *(float2*)(nsum + si) = make_float2(pn0, pn1);
    *(float2*)(dsum + si) = make_float2(pd0, pd1);
    pn0 = dT0 * pn0 + Sn.x;  pn1 = dT1 * pn1 + Sn.y;
    pd0 = dT0 * pd0 + Sd.x;  pd1 = dT1 * pd1 + Sd.y;
  }
}

__global__ __launch_bounds__(256) void wkv_apply(
    const __bf16* __restrict__ kb, const __bf16* __restrict__ vb,
    __bf16* __restrict__ rb,
    const float* __restrict__ td, const float* __restrict__ tf,
    const float* __restrict__ nsum, const float* __restrict__ dsum) {
  const int c0 = (blockIdx.x * 256 + threadIdx.x) * 2;
  const int chunk = blockIdx.y;
  const int b = blockIdx.z;
  const float dc0 = __expf(-__expf(td[c0]));
  const float dc1 = __expf(-__expf(td[c0 + 1]));
  const float fi0 = __expf(tf[c0]);
  const float fi1 = __expf(tf[c0 + 1]);

  const size_t si = (size_t)(chunk * BB + b) * CDIM + c0;
  float2 pn = *(const float2*)(nsum + si);
  float2 pd = *(const float2*)(dsum + si);
  float n0 = pn.x, n1 = pn.y, d0 = pd.x, d1 = pd.y;

  size_t base = ((size_t)b * TSEQ + (size_t)chunk * TCHUNK) * CDIM + c0;
#pragma unroll 2
  for (int t = 0; t < TCHUNK; ++t) {
    const size_t idx = base + (size_t)t * CDIM;
    bf16x2 k2 = *(const bf16x2*)(kb + idx);
    bf16x2 v2 = *(const bf16x2*)(vb + idx);
    bf16x2 r2 = *(const bf16x2*)(rb + idx);
    float k0f = fminf(fmaxf((float)k2[0], -10.f), 10.f);
    float k1f = fminf(fmaxf((float)k2[1], -10.f), 10.f);
    float w0 = __expf(k0f), w1 = __expf(k1f);
    if (chunk == 0 && t == 0) { w0 *= fi0; w1 *= fi1; }
    n0 = dc0 * n0 + w0 * (float)v2[0];
    d0 = dc0 * d0 + w0;
    n1 = dc1 * n1 + w1 * (float)v2[1];
    d1 = dc1 * d1 + w1;
    const float wkv0 = n0 * __builtin_amdgcn_rcpf(d0 + 1e-6f);
    const float wkv1 = n1 * __builtin_amdgcn_rcpf(d1 + 1e-6f);
    const float sr0 = __builtin_amdgcn_rcpf(1.f + __expf(-(float)r2[0]));
    const float sr1 = __builtin_amdgcn_rcpf(1.f + __expf(-(float)r2[1]));
    bf16x2 o;
    o[0] = (__bf16)(sr0 * wkv0);
    o[1] = (__bf16)(sr1 * wkv1);
    *(bf16x2*)(rb + idx) = o;
  }
}

// ---------------- launch -------------------------------------------------------
extern "C" void kernel_launch(void* const* d_in, const int* in_sizes, int n_in,
                              void* d_out, int out_size, void* d_ws, size_t ws_size,
                              hipStream_t stream) {
  const float* x  = (const float*)d_in[0];
  const float* Wk = (const float*)d_in[1];
  const float* Wv = (const float*)d_in[2];
  const float* Wr = (const float*)d_in[3];
  const float* Wo = (const float*)d_in[4];
  const float* td = (const float*)d_in[5];
  const float* tf = (const float*)d_in[6];
  float* out = (float*)d_out;

  char* ws = (char*)d_ws;
  const size_t matX = (size_t)MDIM * KDIM * sizeof(__bf16);  // 33.5 MB
  const size_t matW = (size_t)NDIM * KDIM * sizeof(__bf16);  // 8.4 MB
  __bf16* xb  = (__bf16*)(ws);
  __bf16* wkb = (__bf16*)(ws + matX);
  __bf16* wvb = (__bf16*)(ws + matX + matW);
  __bf16* wrb = (__bf16*)(ws + matX + 2 * matW);
  __bf16* wob = (__bf16*)(ws + matX + 3 * matW);
  __bf16* kb  = (__bf16*)(ws + matX + 4 * matW);
  __bf16* vb  = (__bf16*)(ws + 2 * matX + 4 * matW);
  __bf16* rb  = (__bf16*)(ws + 3 * matX + 4 * matW);
  float* nsum = (float*)(ws + 4 * matX + 4 * matW);
  float* dsum = nsum + (size_t)NCHUNK * BB * CDIM;

  dim3 blk(256);
  dim3 blk5(512);
  cvt_all<<<dim3(NDIM * KDIM / (8 * 256), 8), blk, 0, stream>>>(
      x, Wk, Wv, Wr, Wo, xb, wkb, wvb, wrb, wob);

  dim3 gq(MDIM / 256, NDIM / 256, 3);
  gemm_qkv<<<gq, blk5, 0, stream>>>(xb, wkb, wvb, wrb, kb, vb, rb);
  dim3 gw(CDIM / 512, NCHUNK, BB);
  wkv_summary<<<gw, blk, 0, stream>>>(kb, vb, td, tf, nsum, dsum);
  wkv_scan<<<dim3(CDIM / 512, BB), blk, 0, stream>>>(td, nsum, dsum);
  wkv_apply<<<gw, blk, 0, stream>>>(kb, vb, rb, td, tf, nsum, dsum);
  dim3 go(MDIM / 256, NDIM / 256, 1);
  gemm_o<<<go, blk5, 0, stream>>>(rb, wob, out);
}

// Round 4
// 465.790 us; speedup vs baseline: 1.0346x; 1.0057x over previous
//
#include <hip/hip_runtime.h>
#include <hip/hip_bf16.h>

using bf16 = __hip_bfloat16;
using floatx4 = __attribute__((ext_vector_type(4))) float;
using bf16x8  = __attribute__((ext_vector_type(8))) __bf16;
using bf16x2  = __attribute__((ext_vector_type(2))) __bf16;

#define MDIM 8192   // B*T
#define NDIM 2048   // C
#define KDIM 2048   // C
#define TSEQ 2048   // T
#define BB   4      // batch
#define CDIM 2048   // C
#define NCHUNK 64
#define TCHUNK 32   // TSEQ/NCHUNK

typedef __attribute__((address_space(1))) void gvoid_t;
typedef __attribute__((address_space(3))) void lvoid_t;

__device__ __forceinline__ void load_lds16(const void* g, void* l) {
  __builtin_amdgcn_global_load_lds((gvoid_t*)(void*)g, (lvoid_t*)l, 16, 0, 0);
}

// ---------------- fp32 -> bf16 convert: all 5 matrices, one launch ------------
__global__ __launch_bounds__(256) void cvt_all(
    const float* __restrict__ x,
    const float* __restrict__ Wk, const float* __restrict__ Wv,
    const float* __restrict__ Wr, const float* __restrict__ Wo,
    __bf16* __restrict__ xb,
    __bf16* __restrict__ wkb, __bf16* __restrict__ wvb,
    __bf16* __restrict__ wrb, __bf16* __restrict__ wob) {
  const size_t WN = (size_t)NDIM * KDIM;
  const int slice = blockIdx.y;
  const float* s;
  __bf16* d;
  if (slice < 4) { s = x + (size_t)slice * WN; d = xb + (size_t)slice * WN; }
  else {
    s = (slice == 4) ? Wk : (slice == 5) ? Wv : (slice == 6) ? Wr : Wo;
    d = (slice == 4) ? wkb : (slice == 5) ? wvb : (slice == 6) ? wrb : wob;
  }
  const int i = (blockIdx.x * 256 + threadIdx.x) * 8;
  float4 a = *(const float4*)(s + i);
  float4 b = *(const float4*)(s + i + 4);
  bf16x8 o;
  o[0] = (__bf16)a.x; o[1] = (__bf16)a.y; o[2] = (__bf16)a.z; o[3] = (__bf16)a.w;
  o[4] = (__bf16)b.x; o[5] = (__bf16)b.y; o[6] = (__bf16)b.z; o[7] = (__bf16)b.w;
  *(bf16x8*)(d + i) = o;
}

// ---------------- GEMM: C[m,n] = sum_k A[m,k] * B[n,k], bf16 in, fp32 acc -----
// 256x256 tile, BK=32, 512 threads = 8 waves (2 M x 4 N), per-wave 128x64 out.
//
// R4 structural change: ONE barrier + ONE counted vmcnt per K-tile (was 4+1).
// QUAD-BUFFERED LDS (4 x 32 KiB) is what makes this provably safe:
//   Tile t body: { RD_AF, RD_BF0, STG_A(t+3), MFMA16(0),
//                  RD_BF1, STG_B(t+3), MFMA16(2), vmcnt(8), s_barrier }.
//   - Reads of buf t complete (lgkm-drain before their MFMA) before the wave
//     reaches barrier(t).
//   - STG into buf (t+3)&3 = (t-1)&3 is issued in tile t, i.e. AFTER
//     barrier(t-1) -- one full barrier after that buffer's last read.
//   - vmcnt(8) at tile-t end retires exactly A/B(t+1) (12 in flight -> 8);
//     barrier(t) makes that cross-wave before any tile-t+1 read.
//   Tails: vmcnt(4) at NT-3, vmcnt(0) at NT-2, nothing at NT-1.
// No intra-tile barriers => compiler freely interleaves ds_reads / staging /
// MFMA (fine-grained lgkmcnt), and waves drift out of lockstep so one wave's
// LDS burst overlaps another's MFMA burst.
//
// Buffer layout (32 KiB): A [256 rows][64 B] at +0, B same at +16384.
// Row r (64 B) has four 16-B slots; slot sc holds data chunk sc ^ ((r>>1)&3);
// global_load_lds dest stays LINEAR (tid*16), the swizzle is applied to the
// per-lane GLOBAL source address (both-sides-or-neither).  Frag reads
// (ds_read_b128) are a perfect 1 KiB cover per wave -> conflict-free
// (SQ_LDS_BANK_CONFLICT == 0 measured R1-R3).

#define GBARRIER() asm volatile("s_barrier" ::: "memory")
#define VMW8()     asm volatile("s_waitcnt vmcnt(8)" ::: "memory")
#define VMW4()     asm volatile("s_waitcnt vmcnt(4)" ::: "memory")
#define VMW0()     asm volatile("s_waitcnt vmcnt(0)" ::: "memory")

template <typename CT>
__device__ __forceinline__ void gemm256_body(const __bf16* __restrict__ A,
                                             const __bf16* __restrict__ B,
                                             CT* __restrict__ C,
                                             const int bm, const int bn) {
  __shared__ __attribute__((aligned(128))) unsigned char lds[131072];
  const int tid  = threadIdx.x;
  const int lane = tid & 63;
  const int wave = tid >> 6;
  const int wm = wave >> 2;   // 0..1  (M half)
  const int wn = wave & 3;    // 0..3  (N quarter)

  floatx4 acc[8][4] = {};
  bf16x8 af[8], bfr[2];

  // staging: thread tid covers row (tid>>2) of a 128-row half, 16 B at
  // swizzled data chunk ((tid&3) ^ ((tid>>3)&3))
  const int srow = tid >> 2;
  const int scol = ((tid & 3) ^ ((tid >> 3) & 3)) * 8;
  const __bf16* Ag = A + (size_t)(bm * 256 + srow) * KDIM + scol;
  const __bf16* Bg = B + (size_t)(bn * 256 + srow) * KDIM + scol;
  const uint32_t sdst = (uint32_t)tid * 16u;

  // frag-read lane offset: row (lane&15), slot (lane>>4) ^ ((lane>>1)&3)
  const uint32_t laneoff =
      (uint32_t)((lane & 15) * 64 + (((lane >> 4) ^ ((lane >> 1) & 3)) * 16));
  const uint32_t aoff = (uint32_t)(wm * 8192) + laneoff;
  const uint32_t boff = 16384u + (uint32_t)(wn * 4096) + laneoff;

#define BUF(t_) ((uint32_t)((t_) & 3) * 32768u)
#define STG_A(t_) {                                                           \
  load_lds16(Ag + (size_t)(t_) * 32,                                          \
             (void*)(lds + BUF(t_) + sdst));                                  \
  load_lds16(Ag + (size_t)128 * KDIM + (size_t)(t_) * 32,                     \
             (void*)(lds + BUF(t_) + 8192u + sdst)); }
#define STG_B(t_) {                                                           \
  load_lds16(Bg + (size_t)(t_) * 32,                                          \
             (void*)(lds + BUF(t_) + 16384u + sdst));                         \
  load_lds16(Bg + (size_t)128 * KDIM + (size_t)(t_) * 32,                     \
             (void*)(lds + BUF(t_) + 24576u + sdst)); }
#define RD_AF(bo_) {                                                          \
  const uint32_t ab = (bo_) + aoff;                                           \
  af[0] = *(const bf16x8*)(lds + ab);        af[1] = *(const bf16x8*)(lds + ab + 1024); \
  af[2] = *(const bf16x8*)(lds + ab + 2048); af[3] = *(const bf16x8*)(lds + ab + 3072); \
  af[4] = *(const bf16x8*)(lds + ab + 4096); af[5] = *(const bf16x8*)(lds + ab + 5120); \
  af[6] = *(const bf16x8*)(lds + ab + 6144); af[7] = *(const bf16x8*)(lds + ab + 7168); }
#define RD_BF(bo_, nh_) {                                                     \
  const uint32_t bb = (bo_) + boff + (nh_) * 2048u;                           \
  bfr[0] = *(const bf16x8*)(lds + bb);                                        \
  bfr[1] = *(const bf16x8*)(lds + bb + 1024); }
#define MFMA16(j0_) {                                                         \
  __builtin_amdgcn_s_setprio(1);                                              \
  _Pragma("unroll")                                                           \
  for (int m_ = 0; m_ < 8; ++m_) {                                            \
    acc[m_][(j0_)]     = __builtin_amdgcn_mfma_f32_16x16x32_bf16(af[m_], bfr[0], acc[m_][(j0_)], 0, 0, 0);     \
    acc[m_][(j0_) + 1] = __builtin_amdgcn_mfma_f32_16x16x32_bf16(af[m_], bfr[1], acc[m_][(j0_) + 1], 0, 0, 0); \
  }                                                                           \
  __builtin_amdgcn_s_setprio(0); }

  // ---- prologue: stage tiles 0,1,2 (12 loads); prove tile 0
  STG_A(0); STG_B(0);
  STG_A(1); STG_B(1);
  STG_A(2); STG_B(2);
  VMW8();        // retires A(0)+B(0); tiles 1,2 stay in flight
  GBARRIER();

  constexpr int NT = KDIM / 32;   // 64
  for (int t = 0; t < NT - 3; ++t) {
    const uint32_t bo = BUF(t);
    RD_AF(bo); RD_BF(bo, 0);
    STG_A(t + 3);
    MFMA16(0);
    RD_BF(bo, 1);
    STG_B(t + 3);
    MFMA16(2);
    VMW8();      // 12 in flight -> 8: proves tile t+1 staged
    GBARRIER();  // cross-wave: t+1 readable, buf(t) reads all done
  }
  { // ---- tile NT-3: no staging; prove NT-2 (8 in flight -> 4)
    const uint32_t bo = BUF(NT - 3);
    RD_AF(bo); RD_BF(bo, 0);
    MFMA16(0);
    RD_BF(bo, 1);
    MFMA16(2);
    VMW4();
    GBARRIER();
  }
  { // ---- tile NT-2: prove NT-1 (loads 2+ tiles old -> cheap drain)
    const uint32_t bo = BUF(NT - 2);
    RD_AF(bo); RD_BF(bo, 0);
    MFMA16(0);
    RD_BF(bo, 1);
    MFMA16(2);
    VMW0();
    GBARRIER();
  }
  { // ---- tile NT-1: nothing outstanding
    const uint32_t bo = BUF(NT - 1);
    RD_AF(bo); RD_BF(bo, 0);
    MFMA16(0);
    RD_BF(bo, 1);
    MFMA16(2);
  }

  // C/D layout: col = lane&15, row = (lane>>4)*4 + reg
  const int crow = (lane >> 4) * 4;
  const int ccol = lane & 15;
#pragma unroll
  for (int i = 0; i < 8; ++i)
#pragma unroll
    for (int j = 0; j < 4; ++j) {
      const size_t r0 = (size_t)(bm * 256 + wm * 128 + i * 16 + crow);
      const int    c0 = bn * 256 + wn * 64 + j * 16 + ccol;
#pragma unroll
      for (int rg = 0; rg < 4; ++rg)
        C[(r0 + rg) * NDIM + c0] = (CT)(acc[i][j][rg]);
    }
#undef BUF
#undef STG_A
#undef STG_B
#undef RD_AF
#undef RD_BF
#undef MFMA16
}

// XCD-aware bijective swizzle: each XCD owns one bn column per z-slice ->
// its B-panels stay L2-resident.
__device__ __forceinline__ void xcd_swz(int& bm, int& bn) {
  const int f = (int)(blockIdx.y * 32 + blockIdx.x);   // 0..255
  const int s = (f & 7) * 32 + (f >> 3);
  bm = s & 31;
  bn = s >> 5;
}

__global__ __launch_bounds__(512, 2) void gemm_qkv(const __bf16* __restrict__ x,
                                                   const __bf16* __restrict__ Wk,
                                                   const __bf16* __restrict__ Wv,
                                                   const __bf16* __restrict__ Wr,
                                                   __bf16* __restrict__ kb,
                                                   __bf16* __restrict__ vb,
                                                   __bf16* __restrict__ rb) {
  const __bf16* Bsel = (blockIdx.z == 0) ? Wk : (blockIdx.z == 1) ? Wv : Wr;
  __bf16*       Csel = (blockIdx.z == 0) ? kb : (blockIdx.z == 1) ? vb : rb;
  int bm, bn; xcd_swz(bm, bn);
  gemm256_body<__bf16>(x, Bsel, Csel, bm, bn);
}

__global__ __launch_bounds__(512, 2) void gemm_o(const __bf16* __restrict__ A,
                                                 const __bf16* __restrict__ B,
                                                 float* __restrict__ C) {
  int bm, bn; xcd_swz(bm, bn);
  gemm256_body<float>(A, B, C, bm, bn);
}

// ---------------- WKV blocked scan (3-phase), 2 channels/thread ----------------
__global__ __launch_bounds__(256) void wkv_summary(
    const __bf16* __restrict__ kb, const __bf16* __restrict__ vb,
    const float* __restrict__ td, const float* __restrict__ tf,
    float* __restrict__ nsum, float* __restrict__ dsum) {
  const int c0 = (blockIdx.x * 256 + threadIdx.x) * 2;
  const int chunk = blockIdx.y;
  const int b = blockIdx.z;
  const float dc0 = __expf(-__expf(td[c0]));
  const float dc1 = __expf(-__expf(td[c0 + 1]));
  const float fi0 = __expf(tf[c0]);
  const float fi1 = __expf(tf[c0 + 1]);
  size_t base = ((size_t)b * TSEQ + (size_t)chunk * TCHUNK) * CDIM + c0;
  float n0 = 0.f, d0 = 0.f, n1 = 0.f, d1 = 0.f;
#pragma unroll 4
  for (int t = 0; t < TCHUNK; ++t) {
    bf16x2 k2 = *(const bf16x2*)(kb + base + (size_t)t * CDIM);
    bf16x2 v2 = *(const bf16x2*)(vb + base + (size_t)t * CDIM);
    float k0f = fminf(fmaxf((float)k2[0], -10.f), 10.f);
    float k1f = fminf(fmaxf((float)k2[1], -10.f), 10.f);
    float w0 = __expf(k0f), w1 = __expf(k1f);
    if (chunk == 0 && t == 0) { w0 *= fi0; w1 *= fi1; }
    n0 = dc0 * n0 + w0 * (float)v2[0];
    d0 = dc0 * d0 + w0;
    n1 = dc1 * n1 + w1 * (float)v2[1];
    d1 = dc1 * d1 + w1;
  }
  const size_t si = (size_t)(chunk * BB + b) * CDIM + c0;
  *(float2*)(nsum + si) = make_float2(n0, n1);
  *(float2*)(dsum + si) = make_float2(d0, d1);
}

__global__ __launch_bounds__(256) void wkv_scan(
    const float* __restrict__ td,
    float* __restrict__ nsum, float* __restrict__ dsum) {
  const int c0 = (blockIdx.x * 256 + threadIdx.x) * 2;
  const int b = blockIdx.y;
  const float dT0 = __expf(-__expf(td[c0]) * (float)TCHUNK);
  const float dT1 = __expf(-__expf(td[c0 + 1]) * (float)TCHUNK);
  float pn0 = 0.f, pd0 = 0.f, pn1 = 0.f, pd1 = 0.f;
  for (int j = 0; j < NCHUNK; ++j) {
    const size_t si = (size_t)(j * BB + b) * CDIM + c0;
    float2 Sn = *(const float2*)(nsum + si);
    float2 Sd = *(const float2*)(dsum + si);
    *(float2*)(nsum + si) = make_float2(pn0, pn1);
    *(float2*)(dsum + si) = make_float2(pd0, pd1);
    pn0 = dT0 * pn0 + Sn.x;  pn1 = dT1 * pn1 + Sn.y;
    pd0 = dT0 * pd0 + Sd.x;  pd1 = dT1 * pd1 + Sd.y;
  }
}

__global__ __launch_bounds__(256) void wkv_apply(
    const __bf16* __restrict__ kb, const __bf16* __restrict__ vb,
    __bf16* __restrict__ rb,
    const float* __restrict__ td, const float* __restrict__ tf,
    const float* __restrict__ nsum, const float* __restrict__ dsum) {
  const int c0 = (blockIdx.x * 256 + threadIdx.x) * 2;
  const int chunk = blockIdx.y;
  const int b = blockIdx.z;
  const float dc0 = __expf(-__expf(td[c0]));
  const float dc1 = __expf(-__expf(td[c0 + 1]));
  const float fi0 = __expf(tf[c0]);
  const float fi1 = __expf(tf[c0 + 1]);

  const size_t si = (size_t)(chunk * BB + b) * CDIM + c0;
  float2 pn = *(const float2*)(nsum + si);
  float2 pd = *(const float2*)(dsum + si);
  float n0 = pn.x, n1 = pn.y, d0 = pd.x, d1 = pd.y;

  size_t base = ((size_t)b * TSEQ + (size_t)chunk * TCHUNK) * CDIM + c0;
#pragma unroll 2
  for (int t = 0; t < TCHUNK; ++t) {
    const size_t idx = base + (size_t)t * CDIM;
    bf16x2 k2 = *(const bf16x2*)(kb + idx);
    bf16x2 v2 = *(const bf16x2*)(vb + idx);
    bf16x2 r2 = *(const bf16x2*)(rb + idx);
    float k0f = fminf(fmaxf((float)k2[0], -10.f), 10.f);
    float k1f = fminf(fmaxf((float)k2[1], -10.f), 10.f);
    float w0 = __expf(k0f), w1 = __expf(k1f);
    if (chunk == 0 && t == 0) { w0 *= fi0; w1 *= fi1; }
    n0 = dc0 * n0 + w0 * (float)v2[0];
    d0 = dc0 * d0 + w0;
    n1 = dc1 * n1 + w1 * (float)v2[1];
    d1 = dc1 * d1 + w1;
    const float wkv0 = n0 * __builtin_amdgcn_rcpf(d0 + 1e-6f);
    const float wkv1 = n1 * __builtin_amdgcn_rcpf(d1 + 1e-6f);
    const float sr0 = __builtin_amdgcn_rcpf(1.f + __expf(-(float)r2[0]));
    const float sr1 = __builtin_amdgcn_rcpf(1.f + __expf(-(float)r2[1]));
    bf16x2 o;
    o[0] = (__bf16)(sr0 * wkv0);
    o[1] = (__bf16)(sr1 * wkv1);
    *(bf16x2*)(rb + idx) = o;
  }
}

// ---------------- launch -------------------------------------------------------
extern "C" void kernel_launch(void* const* d_in, const int* in_sizes, int n_in,
                              void* d_out, int out_size, void* d_ws, size_t ws_size,
                              hipStream_t stream) {
  const float* x  = (const float*)d_in[0];
  const float* Wk = (const float*)d_in[1];
  const float* Wv = (const float*)d_in[2];
  const float* Wr = (const float*)d_in[3];
  const float* Wo = (const float*)d_in[4];
  const float* td = (const float*)d_in[5];
  const float* tf = (const float*)d_in[6];
  float* out = (float*)d_out;

  char* ws = (char*)d_ws;
  const size_t matX = (size_t)MDIM * KDIM * sizeof(__bf16);  // 33.5 MB
  const size_t matW = (size_t)NDIM * KDIM * sizeof(__bf16);  // 8.4 MB
  __bf16* xb  = (__bf16*)(ws);
  __bf16* wkb = (__bf16*)(ws + matX);
  __bf16* wvb = (__bf16*)(ws + matX + matW);
  __bf16* wrb = (__bf16*)(ws + matX + 2 * matW);
  __bf16* wob = (__bf16*)(ws + matX + 3 * matW);
  __bf16* kb  = (__bf16*)(ws + matX + 4 * matW);
  __bf16* vb  = (__bf16*)(ws + 2 * matX + 4 * matW);
  __bf16* rb  = (__bf16*)(ws + 3 * matX + 4 * matW);
  float* nsum = (float*)(ws + 4 * matX + 4 * matW);
  float* dsum = nsum + (size_t)NCHUNK * BB * CDIM;

  dim3 blk(256);
  dim3 blk5(512);
  cvt_all<<<dim3(NDIM * KDIM / (8 * 256), 8), blk, 0, stream>>>(
      x, Wk, Wv, Wr, Wo, xb, wkb, wvb, wrb, wob);

  dim3 gq(MDIM / 256, NDIM / 256, 3);
  gemm_qkv<<<gq, blk5, 0, stream>>>(xb, wkb, wvb, wrb, kb, vb, rb);
  dim3 gw(CDIM / 512, NCHUNK, BB);
  wkv_summary<<<gw, blk, 0, stream>>>(kb, vb, td, tf, nsum, dsum);
  wkv_scan<<<dim3(CDIM / 512, BB), blk, 0, stream>>>(td, nsum, dsum);
  wkv_apply<<<gw, blk, 0, stream>>>(kb, vb, rb, td, tf, nsum, dsum);
  dim3 go(MDIM / 256, NDIM / 256, 1);
  gemm_o<<<go, blk5, 0, stream>>>(rb, wob, out);
}